// Round 11
// baseline (43.926 us; speedup 1.0000x reference)
//
#include <hip/hip_runtime.h>

// SigKernel: X (32,256,8) f32, Y (32,256,8) f32 -> out (32,32) f32.
// refinement=1.0 => interpolation identity; scale=1.0 => a_ij = dot(dX[i-1], dY[j-1]).
// Goursat PDE on 256x256 grid, boundary K[i][0]=K[0][j]=1:
//   f1 = 1 + a/2 + a^2/12, f2 = 1 - a^2/12
//   K[i][j] = (K[i][j-1] + K[i-1][j])*f1 - K[i-1][j-1]*f2 ; out = K[255][255]
//
// 1 wave per pair, lane l owns rows 4l+1..4l+4, skewed march (step s, lane l
// -> col j = s-l), branch-free edges via zero-padded dy (r5-verified).
// Round-11: same dataflow as r10 (distance-2 factor pipeline, 3 rotating
// dy/factor sets) restructured for SCHEDULER FREEDOM:
//  - all-scalar math (no asm pk): 4 independent 8-deep fma chains per BUILD
//  - body order: loads -> BUILD(s+2) -> RECURRENCE(s); the loop-carried
//    K-chain sits at body end (next body's dpp gets ~1 body of slack)
//  - 6-step unrolled body (2 rotations), one pld bump per 6 steps, all
//    ds_read offsets compile-time constants.

typedef float f32x4 __attribute__((ext_vector_type(4)));

#define MM   255
#define DYST 9            // odd float stride -> conflict-free b32 LDS reads
#define DYSZ 3456         // max read idx 3454 (lane 0, s=318 loads dy(321))
#define C12f 0.0833333333f

// dst[l] = (l==0) ? old : x[l-1]  (wave_shr:1, bound_ctrl=0). HW-verified r5-r10.
static __device__ inline float dpp_shr1(float old, float x) {
    int r = __builtin_amdgcn_update_dpp(
        __float_as_int(old), __float_as_int(x), 0x138, 0xF, 0xF, false);
    return __int_as_float(r);
}

struct DSet { float d[8]; };
struct FSet { float f1[4]; float f2[4]; };

__global__ __launch_bounds__(64) void sigker_sched(
    const float* __restrict__ X,
    const float* __restrict__ Y,
    float* __restrict__ out)
{
    const int pair = blockIdx.x;      // 0..1023
    const int ax = pair >> 5;
    const int by = pair & 31;
    const int l  = threadIdx.x;       // 0..63

    __shared__ float dYs[DYSZ];

    const float* Xa = X + ax * 2048;
    const float* Yb = Y + by * 2048;

    // Zero-fill (vec4), then stage real dY increments at (ji+63)*9 + c.
    {
        f32x4* dz = (f32x4*)dYs;
        #pragma unroll
        for (int v = l; v < DYSZ / 4; v += 64) dz[v] = (f32x4){0, 0, 0, 0};
    }
    __syncthreads();
    for (int v = l; v < MM * 8; v += 64) {
        const int j = v >> 3, c = v & 7;
        dYs[(j + 63) * DYST + c] = Yb[(j + 1) * 8 + c] - Yb[j * 8 + c];
    }

    // dx rows 4l+1..4l+4 from contiguous window [4l*8, 4l*8+40) of Xa.
    float dx[4][8];                   // all accesses statically unrolled
    {
        f32x4 f[10];
        const f32x4* Xv = (const f32x4*)(Xa + l * 32);
        #pragma unroll
        for (int k = 0; k < 8; ++k) f[k] = Xv[k];
        f[8] = (l < 63) ? Xv[8] : (f32x4){0, 0, 0, 0};
        f[9] = (l < 63) ? Xv[9] : (f32x4){0, 0, 0, 0};
        #pragma unroll
        for (int r = 0; r < 4; ++r) {
            #pragma unroll
            for (int c = 0; c < 8; ++c) {
                const int e0 = r * 8 + c;
                const int e1 = e0 + 8;
                dx[r][c] = f[e1 >> 2][e1 & 3] - f[e0 >> 2][e0 & 3];
            }
        }
    }
    __syncthreads();

    // dy(s) lives at dYs[base + (s-1)*9 .. +7], base = (63-l)*9.
    const int base = (63 - l) * DYST;

    DSet DA, DB, DC;
    FSet F0, F1, F2;
    float K0 = 1.0f, K1 = 1.0f, K2 = 1.0f, K3 = 1.0f, upd = 1.0f;

#define LOADDY(D, P, KOFF) do {                                              \
    _Pragma("unroll")                                                        \
    for (int c = 0; c < 8; ++c) D.d[c] = (P)[(KOFF) * DYST + c];             \
} while (0)

#define BUILD(FB, D) do {                                                    \
    float aa_[4];                                                            \
    _Pragma("unroll")                                                        \
    for (int r = 0; r < 4; ++r) {                                            \
        float t_ = dx[r][0] * D.d[0];                                        \
        _Pragma("unroll")                                                    \
        for (int c = 1; c < 8; ++c) t_ = fmaf(dx[r][c], D.d[c], t_);         \
        aa_[r] = t_;                                                         \
    }                                                                        \
    _Pragma("unroll")                                                        \
    for (int r = 0; r < 4; ++r) {                                            \
        const float q_ = aa_[r] * aa_[r];                                    \
        FB.f1[r] = fmaf(q_, C12f, fmaf(aa_[r], 0.5f, 1.0f));                 \
        FB.f2[r] = fmaf(q_, -C12f, 1.0f);                                    \
    }                                                                        \
} while (0)

    // One step: load dy(s+3) into DLD, build factors(s+2) from DCS (loaded
    // last body), then recurrence(s) with FU (built two bodies ago).
#define STEP(DLD, DCS, FU, FB, KOFF) do {                                    \
    LOADDY(DLD, pld, KOFF);                                                  \
    BUILD(FB, DCS);                                                          \
    const float up_ = dpp_shr1(1.0f, K3);                                    \
    const float t0_ = upd * FU.f2[0];                                        \
    const float t1_ = K0  * FU.f2[1];                                        \
    const float t2_ = K1  * FU.f2[2];                                        \
    const float t3_ = K2  * FU.f2[3];                                        \
    const float c0_ = fmaf(K0, FU.f1[0], -t0_);                              \
    const float c1_ = fmaf(K1, FU.f1[1], -t1_);                              \
    const float c2_ = fmaf(K2, FU.f1[2], -t2_);                              \
    const float c3_ = fmaf(K3, FU.f1[3], -t3_);                              \
    const float k0_ = fmaf(up_, FU.f1[0], c0_);                              \
    const float k1_ = fmaf(k0_, FU.f1[1], c1_);                              \
    const float k2_ = fmaf(k1_, FU.f1[2], c2_);                              \
    const float k3_ = fmaf(k2_, FU.f1[3], c3_);                              \
    upd = up_; K0 = k0_; K1 = k1_; K2 = k2_; K3 = k3_;                       \
} while (0)

    // Prologue: dy(1)->DB, dy(2)->DC, dy(3)->DA; factors(1)->F0, (2)->F1.
    LOADDY(DB, dYs + base, 0);
    LOADDY(DC, dYs + base, 1);
    LOADDY(DA, dYs + base, 2);
    BUILD(F0, DB);
    BUILD(F1, DC);
    const float* pld = dYs + base + 3 * DYST;   // body s=1 loads dy(4)

    // 318 steps = 53 x 6 (two period-3 set rotations per body):
    //  s%3==1: Dld=DB Dcs=DA Fuse=F0 Fbld=F2
    //  s%3==2: Dld=DC Dcs=DB Fuse=F1 Fbld=F0
    //  s%3==0: Dld=DA Dcs=DC Fuse=F2 Fbld=F1
    #pragma unroll 1
    for (int it = 0; it < 53; ++it) {
        STEP(DB, DA, F0, F2, 0);
        STEP(DC, DB, F1, F0, 1);
        STEP(DA, DC, F2, F1, 2);
        STEP(DB, DA, F0, F2, 3);
        STEP(DC, DB, F1, F0, 4);
        STEP(DA, DC, F2, F1, 5);
        pld += 6 * DYST;
    }

    // Row 255 = lane 63, local r=2; last real update at s=318 (j=255).
    if (l == 63) out[pair] = K2;

#undef STEP
#undef BUILD
#undef LOADDY
}

extern "C" void kernel_launch(void* const* d_in, const int* in_sizes, int n_in,
                              void* d_out, int out_size, void* d_ws, size_t ws_size,
                              hipStream_t stream)
{
    const float* X = (const float*)d_in[0];
    const float* Y = (const float*)d_in[1];
    float* out = (float*)d_out;
    (void)in_sizes; (void)n_in; (void)out_size; (void)d_ws; (void)ws_size;

    sigker_sched<<<dim3(32 * 32), dim3(64), 0, stream>>>(X, Y, out);
}

// Round 12
// 37.272 us; speedup vs baseline: 1.1785x; 1.1785x over previous
//
#include <hip/hip_runtime.h>

// SigKernel: X (32,256,8) f32, Y (32,256,8) f32 -> out (32,32) f32.
// refinement=1.0 => interpolation identity; scale=1.0 => a_ij = dot(dX[i-1], dY[j-1]).
// Goursat PDE on 256x256 grid, boundary K[i][0]=K[0][j]=1:
//   f1 = 1 + a/2 + a^2/12, f2 = 1 - a^2/12
//   K[i][j] = (K[i][j-1] + K[i-1][j])*f1 - K[i-1][j-1]*f2 ; out = K[255][255]
//
// 1 wave per pair, lane l owns rows 4l+1..4l+4, skewed march (step s, lane l
// -> col j = s-l), branch-free edges via zero-padded dy (r5/r10-verified).
// Round-12: SLOT-MINIMIZED r10. Evidence r5-r11: at 1 wave/SIMD the issue
// cadence is ~4-6cy/instruction-slot regardless of type, so wall time tracks
// the slot count. Changes vs r10:
//  - stride-10 dy layout (even float offsets, 8B aligned) -> LOADDY is
//    4x ds_read_b64 (4 slots) instead of 8x b32 (8). ~4-way bank aliasing
//    is harmless (DS pipe non-binding, r7).
//  - 6-step unrolled body (53 iters), one pointer bump per body, constant
//    LDS offsets folded into instruction immediates.
//  - keeps r10's op_sel pk BUILD (26 pk) and LOAD->REC->BUILD order.

typedef float f32x2 __attribute__((ext_vector_type(2)));
typedef float f32x4 __attribute__((ext_vector_type(4)));

#define MM   255
#define DYST 10           // EVEN float stride -> 8B-aligned b64 loads
#define DYSZ 3840         // max read idx 3837 (lane 0, s=318 loads dy(321))
#define C12f 0.0833333333f

static __device__ inline f32x2 fma2(f32x2 a, f32x2 b, f32x2 c) {
    return __builtin_elementwise_fma(a, b, c);
}

// dst[l] = (l==0) ? old : x[l-1]  (wave_shr:1, bound_ctrl=0). HW-verified r5-r11.
static __device__ inline float dpp_shr1(float old, float x) {
    int r = __builtin_amdgcn_update_dpp(
        __float_as_int(old), __float_as_int(x), 0x138, 0xF, 0xF, false);
    return __int_as_float(r);
}

// Packed ops, op_sel broadcast of one 32-bit half of src1 (r7/r10-verified).
static __device__ inline void pk_mul_bl(f32x2& d, f32x2 a, f32x2 b) {
    asm("v_pk_mul_f32 %0, %1, %2 op_sel:[0,0] op_sel_hi:[1,0]"
        : "=v"(d) : "v"(a), "v"(b));
}
static __device__ inline void pk_fma_bl(f32x2& d, f32x2 a, f32x2 b) {
    asm("v_pk_fma_f32 %0, %1, %2, %0 op_sel:[0,0,0] op_sel_hi:[1,0,1]"
        : "+v"(d) : "v"(a), "v"(b));
}
static __device__ inline void pk_fma_bh(f32x2& d, f32x2 a, f32x2 b) {
    asm("v_pk_fma_f32 %0, %1, %2, %0 op_sel:[0,1,0] op_sel_hi:[1,1,1]"
        : "+v"(d) : "v"(a), "v"(b));
}

struct Fset { f32x2 f1a, f1b, f2a, f2b; };

__global__ __launch_bounds__(64) void sigker_slim(
    const float* __restrict__ X,
    const float* __restrict__ Y,
    float* __restrict__ out)
{
    const int pair = blockIdx.x;      // 0..1023
    const int ax = pair >> 5;
    const int by = pair & 31;
    const int l  = threadIdx.x;       // 0..63

    __shared__ float dYs[DYSZ];

    const float* Xa = X + ax * 2048;
    const float* Yb = Y + by * 2048;

    // Zero-fill (vec4), then stage real dY increments at (ji+63)*10 + c.
    {
        f32x4* dz = (f32x4*)dYs;
        #pragma unroll
        for (int v = l; v < DYSZ / 4; v += 64) dz[v] = (f32x4){0, 0, 0, 0};
    }
    __syncthreads();
    for (int v = l; v < MM * 8; v += 64) {
        const int j = v >> 3, c = v & 7;
        dYs[(j + 63) * DYST + c] = Yb[(j + 1) * 8 + c] - Yb[j * 8 + c];
    }

    // dx rows 4l+1..4l+4: dxp0[c]={r0,r1}, dxp1[c]={r2,r3} per dim c.
    f32x2 dxp0[8], dxp1[8];
    {
        f32x4 f[10];
        const f32x4* Xv = (const f32x4*)(Xa + l * 32);
        #pragma unroll
        for (int k = 0; k < 8; ++k) f[k] = Xv[k];
        f[8] = (l < 63) ? Xv[8] : (f32x4){0, 0, 0, 0};
        f[9] = (l < 63) ? Xv[9] : (f32x4){0, 0, 0, 0};
        #pragma unroll
        for (int c = 0; c < 8; ++c) {
            const float e0 = f[(c)      >> 2][(c)      & 3];
            const float e1 = f[(8 + c)  >> 2][(8 + c)  & 3];
            const float e2 = f[(16 + c) >> 2][(16 + c) & 3];
            const float e3 = f[(24 + c) >> 2][(24 + c) & 3];
            const float e4 = f[(32 + c) >> 2][(32 + c) & 3];
            dxp0[c] = (f32x2){e1 - e0, e2 - e1};
            dxp1[c] = (f32x2){e3 - e2, e4 - e3};
        }
    }
    __syncthreads();

    const f32x2 C12  = { C12f,  C12f};
    const f32x2 CN12 = {-C12f, -C12f};
    const f32x2 CH   = { 0.5f, 0.5f};
    const f32x2 C1   = { 1.0f, 1.0f};

    // dy(s) lives at dYs[base + (s-1)*10 .. +7], base = (63-l)*10.
    const int base = (63 - l) * DYST;

    // D[k] = {dy_{2k}, dy_{2k+1}} via one ds_read_b64 each (8B aligned).
#define LOADDY(D, P, KOFF) do {                                              \
    D[0] = *(const f32x2*)((P) + (KOFF) * DYST + 0);                         \
    D[1] = *(const f32x2*)((P) + (KOFF) * DYST + 2);                         \
    D[2] = *(const f32x2*)((P) + (KOFF) * DYST + 4);                         \
    D[3] = *(const f32x2*)((P) + (KOFF) * DYST + 6);                         \
} while (0)

#define BUILD(FB, D) do {                                                    \
    f32x2 A0_, A1_, B0_, B1_;                                                \
    pk_mul_bl(A0_, dxp0[0], D[0]);  pk_mul_bl(B0_, dxp1[0], D[0]);           \
    pk_fma_bh(A0_, dxp0[1], D[0]);  pk_fma_bh(B0_, dxp1[1], D[0]);           \
    pk_fma_bl(A0_, dxp0[2], D[1]);  pk_fma_bl(B0_, dxp1[2], D[1]);           \
    pk_fma_bh(A0_, dxp0[3], D[1]);  pk_fma_bh(B0_, dxp1[3], D[1]);           \
    pk_mul_bl(A1_, dxp0[4], D[2]);  pk_mul_bl(B1_, dxp1[4], D[2]);           \
    pk_fma_bh(A1_, dxp0[5], D[2]);  pk_fma_bh(B1_, dxp1[5], D[2]);           \
    pk_fma_bl(A1_, dxp0[6], D[3]);  pk_fma_bl(B1_, dxp1[6], D[3]);           \
    pk_fma_bh(A1_, dxp0[7], D[3]);  pk_fma_bh(B1_, dxp1[7], D[3]);           \
    const f32x2 a01_ = A0_ + A1_;                                            \
    const f32x2 a23_ = B0_ + B1_;                                            \
    const f32x2 q01_ = a01_ * a01_, q23_ = a23_ * a23_;                      \
    FB.f1a = fma2(q01_, C12, fma2(a01_, CH, C1));                            \
    FB.f1b = fma2(q23_, C12, fma2(a23_, CH, C1));                            \
    FB.f2a = fma2(q01_, CN12, C1);                                           \
    FB.f2b = fma2(q23_, CN12, C1);                                           \
} while (0)

    // One step: load dy(s+3), recurrence(s) with FU (built 2 bodies ago),
    // build factors(s+2) from DCS (loaded last body).
#define STEP(DLD, DCS, FU, FB, KOFF) do {                                    \
    LOADDY(DLD, pld, KOFF);                                                  \
    const float up_ = dpp_shr1(1.0f, K3);                                    \
    const float t0_ = upd * FU.f2a.x;                                        \
    const float t1_ = K0  * FU.f2a.y;                                        \
    const float t2_ = K1  * FU.f2b.x;                                        \
    const float t3_ = K2  * FU.f2b.y;                                        \
    const float c0_ = fmaf(K0, FU.f1a.x, -t0_);                              \
    const float c1_ = fmaf(K1, FU.f1a.y, -t1_);                              \
    const float c2_ = fmaf(K2, FU.f1b.x, -t2_);                              \
    const float c3_ = fmaf(K3, FU.f1b.y, -t3_);                              \
    const float k0_ = fmaf(up_, FU.f1a.x, c0_);                              \
    const float k1_ = fmaf(k0_, FU.f1a.y, c1_);                              \
    const float k2_ = fmaf(k1_, FU.f1b.x, c2_);                              \
    const float k3_ = fmaf(k2_, FU.f1b.y, c3_);                              \
    upd = up_; K0 = k0_; K1 = k1_; K2 = k2_; K3 = k3_;                       \
    BUILD(FB, DCS);                                                          \
} while (0)

    f32x2 DA[4], DB[4], DC[4];
    Fset F0, F1, F2;
    float K0 = 1.0f, K1 = 1.0f, K2 = 1.0f, K3 = 1.0f, upd = 1.0f;

    // Prologue: dy(1)->DB, dy(2)->DC, dy(3)->DA; factors(1)->F0, (2)->F1.
    LOADDY(DB, dYs + base, 0);
    LOADDY(DC, dYs + base, 1);
    LOADDY(DA, dYs + base, 2);
    BUILD(F0, DB);
    BUILD(F1, DC);
    const float* pld = dYs + base + 3 * DYST;   // body s=1 loads dy(4)

    // 318 steps = 53 x 6 (two period-3 rotations per body):
    //  s%3==1: Dld=DB Dcs=DA Fuse=F0 Fbld=F2
    //  s%3==2: Dld=DC Dcs=DB Fuse=F1 Fbld=F0
    //  s%3==0: Dld=DA Dcs=DC Fuse=F2 Fbld=F1
    #pragma unroll 1
    for (int it = 0; it < 53; ++it) {
        STEP(DB, DA, F0, F2, 0);
        STEP(DC, DB, F1, F0, 1);
        STEP(DA, DC, F2, F1, 2);
        STEP(DB, DA, F0, F2, 3);
        STEP(DC, DB, F1, F0, 4);
        STEP(DA, DC, F2, F1, 5);
        pld += 6 * DYST;
    }

    // Row 255 = lane 63, local r=2; last real update at s=318 (j=255).
    if (l == 63) out[pair] = K2;

#undef STEP
#undef BUILD
#undef LOADDY
}

extern "C" void kernel_launch(void* const* d_in, const int* in_sizes, int n_in,
                              void* d_out, int out_size, void* d_ws, size_t ws_size,
                              hipStream_t stream)
{
    const float* X = (const float*)d_in[0];
    const float* Y = (const float*)d_in[1];
    float* out = (float*)d_out;
    (void)in_sizes; (void)n_in; (void)out_size; (void)d_ws; (void)ws_size;

    sigker_slim<<<dim3(32 * 32), dim3(64), 0, stream>>>(X, Y, out);
}